// Round 4
// baseline (25805.789 us; speedup 1.0000x reference)
//
#include <hip/hip_runtime.h>
#include <hip/hip_bf16.h>
#include <math.h>

// ---- problem constants ----
#define V    32000
#define E    512
#define NH   8
#define DH   64
#define NL   2
#define FF   2048
#define MAXLEN 24
#define S    48
#define B    8
#define TRANS 14
#define INIT 12      // TRANS - 2
#define LF   35      // INIT + MAXLEN - 1

#define NB   256     // persistent grid blocks (co-resident, 1/CU)
#define NT   1024    // threads per block (16 waves)

__device__ inline float wsum(float v) {
#pragma unroll
  for (int off = 32; off; off >>= 1) v += __shfl_xor(v, off);
  return v;
}

// ---- coherence-point (relaxed agent) helpers: no cache-maintenance side effects ----
__device__ inline float ldc(const float* p) {
  return __hip_atomic_load(p, __ATOMIC_RELAXED, __HIP_MEMORY_SCOPE_AGENT);
}
__device__ inline void stc(float* p, float v) {
  __hip_atomic_store(p, v, __ATOMIC_RELAXED, __HIP_MEMORY_SCOPE_AGENT);
}
__device__ inline float2 ldc8(const float* p) {
  union { unsigned long long u; float2 f; } c;
  c.u = __hip_atomic_load((const unsigned long long*)p, __ATOMIC_RELAXED, __HIP_MEMORY_SCOPE_AGENT);
  return c.f;
}
__device__ inline int ldci(const int* p) {
  return __hip_atomic_load(p, __ATOMIC_RELAXED, __HIP_MEMORY_SCOPE_AGENT);
}

// ================= prefill kernels (rounds 1-3, proven) =================

__global__ void embed_init_k(const int* __restrict__ transform, const float* __restrict__ emb,
                             float* __restrict__ xbuf) {
  int t = blockIdx.x;
  int pos = t >> 3, b = t & 7;
  int tok = transform[(1 + pos) * B + b];
  for (int d = threadIdx.x; d < E; d += blockDim.x) {
    double div = exp(-log(10000.0) * (double)(d & ~1) / (double)E);
    double ang = (double)pos * div;
    float pe = (d & 1) ? (float)cos(ang) : (float)sin(ang);
    xbuf[(size_t)t * E + d] = emb[(size_t)tok * E + d] + pe;
  }
}

template <int K>
__global__ __launch_bounds__(256) void gemm_k(
    const float* __restrict__ x, const float* __restrict__ W, const float* __restrict__ bias,
    int ntok, int nout, int route, int relu,
    float* __restrict__ out0, float* __restrict__ out1, float* __restrict__ out2) {
  constexpr int K4 = K / 4;
  constexpr int J  = K / 256;
  __shared__ float4 xt[8][K4];
  const int tid = threadIdx.x;
  const int lane = tid & 63;
  const int o = blockIdx.x * 4 + (tid >> 6);

  float4 wr[J];
  if (o < nout) {
    const float4* Wr = (const float4*)(W + (size_t)o * K);
#pragma unroll
    for (int j = 0; j < J; ++j) wr[j] = Wr[lane + 64 * j];
  }

  const int ng = ntok >> 3;
  for (int g = 0; g < ng; ++g) {
    if (g) __syncthreads();
    const float4* xg = (const float4*)(x + (size_t)g * 8 * K);
    float4* xf = &xt[0][0];
    for (int i = tid; i < 8 * K4; i += 256) xf[i] = xg[i];
    __syncthreads();
    if (o < nout) {
      float acc[8] = {0, 0, 0, 0, 0, 0, 0, 0};
#pragma unroll
      for (int j = 0; j < J; ++j) {
        float4 w = wr[j];
#pragma unroll
        for (int tt = 0; tt < 8; ++tt) {
          float4 xv = xt[tt][lane + 64 * j];
          acc[tt] += w.x * xv.x + w.y * xv.y + w.z * xv.z + w.w * xv.w;
        }
      }
#pragma unroll
      for (int tt = 0; tt < 8; ++tt) acc[tt] = wsum(acc[tt]);
      if (lane == 0) {
        float bo = bias[o];
#pragma unroll
        for (int tt = 0; tt < 8; ++tt) {
          float v = acc[tt] + bo;
          if (relu) v = fmaxf(v, 0.f);
          int t = g * 8 + tt;
          if (route == 0) {
            out0[(size_t)t * nout + o] = v;
          } else if (route == 1) {
            if (o < E) out0[(size_t)t * E + o] = v;
            else if (o < 2 * E) out1[(size_t)t * E + (o - E)] = v;
            else out2[(size_t)t * E + (o - 2 * E)] = v;
          } else {
            if (o < E) out0[(size_t)t * E + o] = v;
            else out1[(size_t)t * E + (o - E)] = v;
          }
        }
      }
    }
  }
}

__global__ __launch_bounds__(256) void attn_k(
    const float* __restrict__ q, const float* __restrict__ Kc, const float* __restrict__ Vc,
    float* __restrict__ outp, int p0, int nq, int nk_fixed, int causal) {
  const int tid = threadIdx.x;
  const int lane = tid & 63;
  const int u = blockIdx.x * 4 + (tid >> 6);
  if (u >= nq * 64) return;
  const int qi = u >> 6;
  const int r = u & 63;
  const int b = r >> 3, h = r & 7;
  const int nk = causal ? (p0 + qi + 1) : nk_fixed;

  const size_t qoff = (size_t)(qi * B + b) * E + h * DH + lane;
  const float qv = q[qoff];

  float myscore = -INFINITY;
  for (int k = 0; k < nk; ++k) {
    float prod = qv * Kc[(size_t)(k * B + b) * E + h * DH + lane];
    prod = wsum(prod);
    if (lane == k) myscore = prod * 0.125f;
  }
  float m = myscore;
#pragma unroll
  for (int off = 32; off; off >>= 1) m = fmaxf(m, __shfl_xor(m, off));
  float p = (lane < nk) ? expf(myscore - m) : 0.f;
  float denom = wsum(p);
  float a = p / denom;

  float oacc = 0.f;
  for (int k = 0; k < nk; ++k) {
    float ak = __shfl(a, k);
    oacc = fmaf(ak, Vc[(size_t)(k * B + b) * E + h * DH + lane], oacc);
  }
  outp[qoff] = oacc;
}

__global__ __launch_bounds__(256) void add_ln_k(
    const float* __restrict__ xa, const float* __restrict__ xb,
    const float* __restrict__ g, const float* __restrict__ beta,
    float* __restrict__ outp, int ntok) {
  const int tid = threadIdx.x, lane = tid & 63;
  const int t = blockIdx.x * 4 + (tid >> 6);
  if (t >= ntok) return;
  float v[8];
  float s = 0.f;
#pragma unroll
  for (int j = 0; j < 8; ++j) {
    int d = lane + 64 * j;
    v[j] = xa[(size_t)t * E + d] + xb[(size_t)t * E + d];
    s += v[j];
  }
  s = wsum(s);
  float mean = s * (1.f / 512.f);
  float d2 = 0.f;
#pragma unroll
  for (int j = 0; j < 8; ++j) { float dd = v[j] - mean; d2 += dd * dd; }
  d2 = wsum(d2);
  float inv = 1.f / sqrtf(d2 * (1.f / 512.f) + 1e-5f);
#pragma unroll
  for (int j = 0; j < 8; ++j) {
    int d = lane + 64 * j;
    outp[(size_t)t * E + d] = (v[j] - mean) * inv * g[d] + beta[d];
  }
}

// ================= persistent autoregressive decode =================
// blocks 0..7: full per-batch decoder (intra-block sync only).
// grid sync per step: x3-ready flag (8 arrivals) + logits-done counter (256 arrivals).

__global__ __launch_bounds__(NT, 1) void decode_persist_k(
    const float* __restrict__ emb,
    const float* __restrict__ sa_w, const float* __restrict__ sa_b,
    const float* __restrict__ sa_ow, const float* __restrict__ sa_ob,
    const float* __restrict__ ca_w, const float* __restrict__ ca_b,
    const float* __restrict__ ca_ow, const float* __restrict__ ca_ob,
    const float* __restrict__ ff1_w, const float* __restrict__ ff1_b,
    const float* __restrict__ ff2_w, const float* __restrict__ ff2_b,
    const float* __restrict__ ln_g, const float* __restrict__ ln_b,
    const float* __restrict__ out_w, const float* __restrict__ out_b,
    float* __restrict__ kself, float* __restrict__ vself,
    const float* __restrict__ kcross, const float* __restrict__ vcross,
    float* __restrict__ x3buf, float* __restrict__ outp, int* __restrict__ bar) {
  __shared__ __align__(16) float s_a[E];     // layer input / x3
  __shared__ __align__(16) float s_b[E];     // kp scratch / x1
  __shared__ __align__(16) float s_c[E];     // vp scratch / x2
  __shared__ __align__(16) float s_q[E];     // q / raw proj scratch
  __shared__ __align__(16) float s_att[E];   // attention output
  __shared__ __align__(16) float s_h[FF];    // ff1 output
  __shared__ __align__(16) float s_tile[8 * E];  // logits x3 tile (8 batches)
  __shared__ float s_rv[NT];
  __shared__ int   s_ri[NT];

  const int tid  = threadIdx.x;
  const int lane = tid & 63;
  const int wv   = tid >> 6;          // wave 0..15
  const int g4   = lane >> 2;         // row-in-group 0..15
  const int s4   = lane & 3;          // K-quarter 0..3
  const int bid  = blockIdx.x;
  const int bb   = bid;               // batch for decoder blocks (<8)

  int* x3ctr  = &bar[0];
  int* x3flag = &bar[32];
  int* donectr = &bar[64];

  // 16-rows-per-wave dot: rows r0..r0+15, input vector in LDS (float4-aligned).
  // returns the row (r0+g4) dot in all 4 lanes of the quarter-group.
  auto dotrows = [&](const float* W, int r0, int K, const float* xin) -> float {
    const float4* Wp = (const float4*)(W + (size_t)(r0 + g4) * K);
    const float4* Xp = (const float4*)xin;
    const int q4 = K >> 4;            // float4s per quarter
    float acc = 0.f;
#pragma unroll 4
    for (int j = 0; j < q4; ++j) {
      float4 w = Wp[s4 * q4 + j];
      float4 x = Xp[s4 * q4 + j];
      acc += w.x * x.x + w.y * x.y + w.z * x.z + w.w * x.w;
    }
    acc += __shfl_xor(acc, 1);
    acc += __shfl_xor(acc, 2);
    return acc;
  };

  // LayerNorm of (xa+xb) over E dims -> dst (LDS). Wave 0 only; caller syncs.
  auto lnorm = [&](const float* xa, const float* xb, int lnidx, float* dst) {
    if (wv == 0) {
      const float* gg = ln_g + (size_t)lnidx * E;
      const float* be = ln_b + (size_t)lnidx * E;
      float v[8];
      float sum = 0.f;
#pragma unroll
      for (int j = 0; j < 8; ++j) {
        int d = lane + 64 * j;
        v[j] = xa[d] + xb[d];
        sum += v[j];
      }
      sum = wsum(sum);
      float mean = sum * (1.f / 512.f);
      float d2 = 0.f;
#pragma unroll
      for (int j = 0; j < 8; ++j) { float dd = v[j] - mean; d2 += dd * dd; }
      d2 = wsum(d2);
      float inv = 1.f / sqrtf(d2 * (1.f / 512.f) + 1e-5f);
#pragma unroll
      for (int j = 0; j < 8; ++j) {
        int d = lane + 64 * j;
        dst[d] = (v[j] - mean) * inv * gg[d] + be[d];
      }
    }
  };

  // attention for batch bb: waves 0..7 = heads; q in s_q, out -> s_att.
  // self: last key/value row from LDS (s_b/s_c), earlier from global cache.
  auto attn_stage = [&](const float* Kc, const float* Vc, int nk, int self) {
    if (wv < 8) {
      const int h = wv;
      const float qv = s_q[h * DH + lane];
      float sc[48];
#pragma unroll
      for (int k = 0; k < 48; ++k) {
        if (k < nk) {
          float kv = (self && k == nk - 1) ? s_b[h * DH + lane]
                                           : Kc[(size_t)(k * B + bb) * E + h * DH + lane];
          sc[k] = qv * kv;
        } else sc[k] = 0.f;
      }
#pragma unroll
      for (int k = 0; k < 48; ++k) if (k < nk) sc[k] = wsum(sc[k]) * 0.125f;
      float m = -INFINITY;
#pragma unroll
      for (int k = 0; k < 48; ++k) if (k < nk) m = fmaxf(m, sc[k]);
      float den = 0.f;
#pragma unroll
      for (int k = 0; k < 48; ++k) {
        float e = (k < nk) ? expf(sc[k] - m) : 0.f;
        sc[k] = e; den += e;
      }
      float inv = 1.f / den;
      float oa = 0.f;
#pragma unroll
      for (int k = 0; k < 48; ++k) {
        if (k < nk) {
          float vv = (self && k == nk - 1) ? s_c[h * DH + lane]
                                           : Vc[(size_t)(k * B + bb) * E + h * DH + lane];
          oa = fmaf(sc[k] * inv, vv, oa);
        }
      }
      s_att[h * DH + lane] = oa;
    }
  };

  for (int i = 0; i < MAXLEN - 1; ++i) {
    const int p = INIT + i;                      // position decoded this step

    if (bid < 8) {
      // ---- wait for step i-1 logits, then argmax row (p-1) for batch bb ----
      if (i > 0) {
        if (tid == 0)
          while (ldci(donectr) < NB * i) __builtin_amdgcn_s_sleep(8);
        __syncthreads();
      }
      {
        const float* row = outp + ((size_t)(p - 1) * B + bb) * V;
        float bv = -INFINITY; int bi = 0x7fffffff;
        for (int j = tid; j < V / 2; j += NT) {
          float2 vv = ldc8(row + 2 * j);
          if (vv.x > bv || (vv.x == bv && 2 * j < bi)) { bv = vv.x; bi = 2 * j; }
          if (vv.y > bv || (vv.y == bv && 2 * j + 1 < bi)) { bv = vv.y; bi = 2 * j + 1; }
        }
        s_rv[tid] = bv; s_ri[tid] = bi;
        __syncthreads();
        for (int st = NT / 2; st; st >>= 1) {
          if (tid < st) {
            float ov = s_rv[tid + st]; int oi = s_ri[tid + st];
            if (ov > s_rv[tid] || (ov == s_rv[tid] && oi < s_ri[tid])) {
              s_rv[tid] = ov; s_ri[tid] = oi;
            }
          }
          __syncthreads();
        }
        const int tok = s_ri[0];
        if (tid < E)
          s_a[tid] = emb[(size_t)tok * E + tid] + ((tid & 1) ? 1.0f : 0.0f);  // + pe[0]
        __syncthreads();
      }

      // ---- 2 decoder layers, all in-block ----
      for (int l = 0; l < NL; ++l) {
        // A: QKV (1536 rows): q->s_q, k->s_b + cache, v->s_c + cache
        for (int r0 = wv * 16; r0 < 3 * E; r0 += 256) {
          float v = dotrows(sa_w + (size_t)l * 3 * E * E, r0, E, s_a);
          int r = r0 + g4;
          if (s4 == 0) {
            v += sa_b[(size_t)l * 3 * E + r];
            if (r < E) s_q[r] = v;
            else if (r < 2 * E) {
              int f = r - E;
              s_b[f] = v;
              stc(&kself[((size_t)(l * LF + p) * B + bb) * E + f], v);
            } else {
              int f = r - 2 * E;
              s_c[f] = v;
              stc(&vself[((size_t)(l * LF + p) * B + bb) * E + f], v);
            }
          }
        }
        __syncthreads();
        // B: self-attention (keys 0..p)
        attn_stage(kself + (size_t)l * LF * B * E, vself + (size_t)l * LF * B * E, p + 1, 1);
        __syncthreads();
        // C: self out-proj -> s_q(raw); LN(s_a + s_q) -> s_b (x1)
        for (int r0 = wv * 16; r0 < E; r0 += 256) {
          float v = dotrows(sa_ow + (size_t)l * E * E, r0, E, s_att);
          int r = r0 + g4;
          if (s4 == 0) s_q[r] = v + sa_ob[(size_t)l * E + r];
        }
        __syncthreads();
        lnorm(s_a, s_q, l * 3 + 0, s_b);
        __syncthreads();
        // D: cross Q-proj (rows 0..E of ca_w) -> s_q; cross-attn
        for (int r0 = wv * 16; r0 < E; r0 += 256) {
          float v = dotrows(ca_w + (size_t)l * 3 * E * E, r0, E, s_b);
          int r = r0 + g4;
          if (s4 == 0) s_q[r] = v + ca_b[(size_t)l * 3 * E + r];
        }
        __syncthreads();
        attn_stage(kcross + (size_t)l * S * B * E, vcross + (size_t)l * S * B * E, S, 0);
        __syncthreads();
        // E: cross out-proj -> s_q; LN(s_b + s_q) -> s_c (x2)
        for (int r0 = wv * 16; r0 < E; r0 += 256) {
          float v = dotrows(ca_ow + (size_t)l * E * E, r0, E, s_att);
          int r = r0 + g4;
          if (s4 == 0) s_q[r] = v + ca_ob[(size_t)l * E + r];
        }
        __syncthreads();
        lnorm(s_b, s_q, l * 3 + 1, s_c);
        __syncthreads();
        // F: ff1 (relu) -> s_h
        for (int r0 = wv * 16; r0 < FF; r0 += 256) {
          float v = dotrows(ff1_w + (size_t)l * FF * E, r0, E, s_c);
          int r = r0 + g4;
          if (s4 == 0) s_h[r] = fmaxf(v + ff1_b[(size_t)l * FF + r], 0.f);
        }
        __syncthreads();
        // G: ff2 -> s_q; LN(s_c + s_q) -> s_a (next layer input / x3)
        for (int r0 = wv * 16; r0 < E; r0 += 256) {
          float v = dotrows(ff2_w + (size_t)l * E * FF, r0, FF, s_h);
          int r = r0 + g4;
          if (s4 == 0) s_q[r] = v + ff2_b[(size_t)l * E + r];
        }
        __syncthreads();
        lnorm(s_c, s_q, l * 3 + 2, s_a);
        __syncthreads();
      }

      // ---- publish x3(bb); last batch block raises the flag ----
      if (tid < E) stc(&x3buf[(size_t)bb * E + tid], s_a[tid]);
      __syncthreads();                 // drain stc (vmcnt 0) before counter
      if (tid == 0) {
        int old = __hip_atomic_fetch_add(x3ctr, 1, __ATOMIC_RELAXED, __HIP_MEMORY_SCOPE_AGENT);
        if (old == 8 * (i + 1) - 1)
          __hip_atomic_store(x3flag, i + 1, __ATOMIC_RELAXED, __HIP_MEMORY_SCOPE_AGENT);
      }
    }

    // ---- all 256 blocks: wait x3, stage tile, logits rows, arrive done ----
    if (tid == 0)
      while (ldci(x3flag) < i + 1) __builtin_amdgcn_s_sleep(16);
    __syncthreads();
    for (int j = tid; j < 8 * E / 2; j += NT) {
      float2 vv = ldc8(x3buf + 2 * j);
      s_tile[2 * j] = vv.x; s_tile[2 * j + 1] = vv.y;
    }
    __syncthreads();
    if (wv < 8) {
      int rb = bid * 8 + wv;                   // 16-row block index, 2000 total
      if (rb < V / 16) {
        int r0 = rb * 16;
        const float4* Wp = (const float4*)(out_w + (size_t)(r0 + g4) * E);
        const float4* Xp = (const float4*)s_tile;
        float acc[8] = {0, 0, 0, 0, 0, 0, 0, 0};
#pragma unroll 4
        for (int j = 0; j < 32; ++j) {
          float4 w = Wp[s4 * 32 + j];
#pragma unroll
          for (int t = 0; t < 8; ++t) {
            float4 x = Xp[t * 128 + s4 * 32 + j];
            acc[t] += w.x * x.x + w.y * x.y + w.z * x.z + w.w * x.w;
          }
        }
#pragma unroll
        for (int t = 0; t < 8; ++t) {
          acc[t] += __shfl_xor(acc[t], 1);
          acc[t] += __shfl_xor(acc[t], 2);
        }
        if (s4 == 0) {
          int r = r0 + g4;
          float bo = out_b[r];
#pragma unroll
          for (int t = 0; t < 8; ++t)
            stc(&outp[((size_t)p * B + t) * V + r], acc[t] + bo);
        }
      }
    }
    __syncthreads();                 // drain logits stores
    if (tid == 0)
      __hip_atomic_fetch_add(donectr, 1, __ATOMIC_RELAXED, __HIP_MEMORY_SCOPE_AGENT);
  }
}

extern "C" void kernel_launch(void* const* d_in, const int* in_sizes, int n_in,
                              void* d_out, int out_size, void* d_ws, size_t ws_size,
                              hipStream_t stream) {
  const float* enc       = (const float*)d_in[0];
  const int*   transform = (const int*)d_in[1];
  const float* emb       = (const float*)d_in[3];
  const float* sa_w  = (const float*)d_in[4];
  const float* sa_b  = (const float*)d_in[5];
  const float* sa_ow = (const float*)d_in[6];
  const float* sa_ob = (const float*)d_in[7];
  const float* ca_w  = (const float*)d_in[8];
  const float* ca_b  = (const float*)d_in[9];
  const float* ca_ow = (const float*)d_in[10];
  const float* ca_ob = (const float*)d_in[11];
  const float* ff1_w = (const float*)d_in[12];
  const float* ff1_b = (const float*)d_in[13];
  const float* ff2_w = (const float*)d_in[14];
  const float* ff2_b = (const float*)d_in[15];
  const float* ln_g  = (const float*)d_in[16];
  const float* ln_b  = (const float*)d_in[17];
  const float* out_w = (const float*)d_in[18];
  const float* out_b = (const float*)d_in[19];
  float* out = (float*)d_out;

  // workspace layout (floats)
  const size_t SELF_SZ  = (size_t)LF * B * E;    // 143360
  const size_t CROSS_SZ = (size_t)S * B * E;     // 196608
  float* ws     = (float*)d_ws;
  float* xbuf   = ws;                            // prefill embeddings [12*B, E]
  float* kself  = xbuf + (size_t)INIT * B * E;
  float* vself  = kself + NL * SELF_SZ;
  float* kcross = vself + NL * SELF_SZ;
  float* vcross = kcross + NL * CROSS_SZ;
  float* act0   = vcross + NL * CROSS_SZ;        // [96,E] prefill / x3buf persist
  float* act1   = act0 + 96 * E;
  float* act2   = act1 + 96 * E;
  float* act3   = act2 + 96 * E;
  float* ffb    = act3 + 96 * E;                 // [96,FF]
  int*   bar    = (int*)(ffb + 96 * FF);         // counters/flags (128B-spaced)
  float* x3buf  = act0;

  hipMemsetAsync(bar, 0, 512, stream);

  // 1) initial embeddings (positions 0..11)
  embed_init_k<<<INIT * B, 128, 0, stream>>>(transform, emb, xbuf);

  // 2) cross-attn K/V caches
  for (int l = 0; l < NL; ++l) {
    gemm_k<E><<<(2 * E) / 4, 256, 0, stream>>>(
        enc, ca_w + ((size_t)l * 3 * E + E) * E, ca_b + (size_t)l * 3 * E + E,
        S * B, 2 * E, 2, 0, kcross + l * CROSS_SZ, vcross + l * CROSS_SZ, nullptr);
  }

  // 3) prefill positions 0..11 (multi-kernel, one-time)
  {
    const int p0 = 0, nq = INIT, ntok = nq * B;
    const float* xin = xbuf;
    for (int l = 0; l < NL; ++l) {
      const float* x = (l == 0) ? xin : act1;
      gemm_k<E><<<(3 * E) / 4, 256, 0, stream>>>(
          x, sa_w + (size_t)l * 3 * E * E, sa_b + (size_t)l * 3 * E, ntok, 3 * E, 1, 0,
          act2, kself + l * SELF_SZ, vself + l * SELF_SZ);
      attn_k<<<nq * 16, 256, 0, stream>>>(act2, kself + l * SELF_SZ, vself + l * SELF_SZ,
                                          act3, p0, nq, 0, 1);
      gemm_k<E><<<E / 4, 256, 0, stream>>>(
          act3, sa_ow + (size_t)l * E * E, sa_ob + (size_t)l * E, ntok, E, 0, 0, act2, nullptr, nullptr);
      add_ln_k<<<(ntok + 3) / 4, 256, 0, stream>>>(
          x, act2, ln_g + (size_t)l * 3 * E, ln_b + (size_t)l * 3 * E, act1, ntok);
      gemm_k<E><<<E / 4, 256, 0, stream>>>(
          act1, ca_w + (size_t)l * 3 * E * E, ca_b + (size_t)l * 3 * E, ntok, E, 0, 0, act2, nullptr, nullptr);
      attn_k<<<nq * 16, 256, 0, stream>>>(act2, kcross + l * CROSS_SZ, vcross + l * CROSS_SZ,
                                          act3, p0, nq, S, 0);
      gemm_k<E><<<E / 4, 256, 0, stream>>>(
          act3, ca_ow + (size_t)l * E * E, ca_ob + (size_t)l * E, ntok, E, 0, 0, act2, nullptr, nullptr);
      add_ln_k<<<(ntok + 3) / 4, 256, 0, stream>>>(
          act1, act2, ln_g + (size_t)l * 3 * E + E, ln_b + (size_t)l * 3 * E + E, act1, ntok);
      gemm_k<E><<<FF / 4, 256, 0, stream>>>(
          act1, ff1_w + (size_t)l * FF * E, ff1_b + (size_t)l * FF, ntok, FF, 0, 1, ffb, nullptr, nullptr);
      gemm_k<FF><<<E / 4, 256, 0, stream>>>(
          ffb, ff2_w + (size_t)l * E * FF, ff2_b + (size_t)l * E, ntok, E, 0, 0, act2, nullptr, nullptr);
      add_ln_k<<<(ntok + 3) / 4, 256, 0, stream>>>(
          act1, act2, ln_g + (size_t)l * 3 * E + 2 * E, ln_b + (size_t)l * 3 * E + 2 * E, act1, ntok);
    }
    gemm_k<E><<<V / 4, 256, 0, stream>>>(
        act1, out_w, out_b, ntok, V, 0, 0, out, nullptr, nullptr);
  }

  // 4) persistent kernel: all 23 autoregressive steps
  decode_persist_k<<<NB, NT, 0, stream>>>(
      emb, sa_w, sa_b, sa_ow, sa_ob, ca_w, ca_b, ca_ow, ca_ob,
      ff1_w, ff1_b, ff2_w, ff2_b, ln_g, ln_b, out_w, out_b,
      kself, vself, kcross, vcross, x3buf, out, bar);
}

// Round 5
// 5298.820 us; speedup vs baseline: 4.8701x; 4.8701x over previous
//
#include <hip/hip_runtime.h>
#include <hip/hip_bf16.h>
#include <math.h>

// ---- problem constants ----
#define V    32000
#define E    512
#define NH   8
#define DH   64
#define NL   2
#define FF   2048
#define MAXLEN 24
#define S    48
#define B    8
#define TRANS 14
#define INIT 12      // TRANS - 2
#define LF   35      // INIT + MAXLEN - 1

#define NB   256     // persistent grid blocks (co-resident, 1/CU)
#define NT   512     // threads per block (8 waves)

typedef float f4 __attribute__((ext_vector_type(4)));

__device__ inline float wsum(float v) {
#pragma unroll
  for (int off = 32; off; off >>= 1) v += __shfl_xor(v, off);
  return v;
}
__device__ inline float wmax(float v) {
#pragma unroll
  for (int off = 32; off; off >>= 1) v = fmaxf(v, __shfl_xor(v, off));
  return v;
}

// ---- coherence-point (relaxed agent) helpers: no cache-maintenance side effects ----
__device__ inline float ldc(const float* p) {
  return __hip_atomic_load(p, __ATOMIC_RELAXED, __HIP_MEMORY_SCOPE_AGENT);
}
__device__ inline void stc(float* p, float v) {
  __hip_atomic_store(p, v, __ATOMIC_RELAXED, __HIP_MEMORY_SCOPE_AGENT);
}
__device__ inline float2 ldc8(const float* p) {
  union { unsigned long long u; float2 f; } c;
  c.u = __hip_atomic_load((const unsigned long long*)p, __ATOMIC_RELAXED, __HIP_MEMORY_SCOPE_AGENT);
  return c.f;
}
__device__ inline void stc8(float* p, float x, float y) {
  union { unsigned long long u; float f[2]; } c; c.f[0] = x; c.f[1] = y;
  __hip_atomic_store((unsigned long long*)p, c.u, __ATOMIC_RELAXED, __HIP_MEMORY_SCOPE_AGENT);
}
__device__ inline int ldci(const int* p) {
  return __hip_atomic_load(p, __ATOMIC_RELAXED, __HIP_MEMORY_SCOPE_AGENT);
}
__device__ inline void stci(int* p, int v) {
  __hip_atomic_store(p, v, __ATOMIC_RELAXED, __HIP_MEMORY_SCOPE_AGENT);
}

#define CMB(v, idx, ov, oi) do { if ((ov) > (v) || ((ov) == (v) && (oi) < (idx))) { (v) = (ov); (idx) = (oi); } } while (0)

// ================= prefill kernels (rounds 1-4, proven) =================

__global__ void embed_init_k(const int* __restrict__ transform, const float* __restrict__ emb,
                             float* __restrict__ xbuf) {
  int t = blockIdx.x;
  int pos = t >> 3, b = t & 7;
  int tok = transform[(1 + pos) * B + b];
  for (int d = threadIdx.x; d < E; d += blockDim.x) {
    double div = exp(-log(10000.0) * (double)(d & ~1) / (double)E);
    double ang = (double)pos * div;
    float pe = (d & 1) ? (float)cos(ang) : (float)sin(ang);
    xbuf[(size_t)t * E + d] = emb[(size_t)tok * E + d] + pe;
  }
}

template <int K>
__global__ __launch_bounds__(256) void gemm_k(
    const float* __restrict__ x, const float* __restrict__ W, const float* __restrict__ bias,
    int ntok, int nout, int route, int relu,
    float* __restrict__ out0, float* __restrict__ out1, float* __restrict__ out2) {
  constexpr int K4 = K / 4;
  constexpr int J  = K / 256;
  __shared__ float4 xt[8][K4];
  const int tid = threadIdx.x;
  const int lane = tid & 63;
  const int o = blockIdx.x * 4 + (tid >> 6);

  float4 wr[J];
  if (o < nout) {
    const float4* Wr = (const float4*)(W + (size_t)o * K);
#pragma unroll
    for (int j = 0; j < J; ++j) wr[j] = Wr[lane + 64 * j];
  }

  const int ng = ntok >> 3;
  for (int g = 0; g < ng; ++g) {
    if (g) __syncthreads();
    const float4* xg = (const float4*)(x + (size_t)g * 8 * K);
    float4* xf = &xt[0][0];
    for (int i = tid; i < 8 * K4; i += 256) xf[i] = xg[i];
    __syncthreads();
    if (o < nout) {
      float acc[8] = {0, 0, 0, 0, 0, 0, 0, 0};
#pragma unroll
      for (int j = 0; j < J; ++j) {
        float4 w = wr[j];
#pragma unroll
        for (int tt = 0; tt < 8; ++tt) {
          float4 xv = xt[tt][lane + 64 * j];
          acc[tt] += w.x * xv.x + w.y * xv.y + w.z * xv.z + w.w * xv.w;
        }
      }
#pragma unroll
      for (int tt = 0; tt < 8; ++tt) acc[tt] = wsum(acc[tt]);
      if (lane == 0) {
        float bo = bias[o];
#pragma unroll
        for (int tt = 0; tt < 8; ++tt) {
          float v = acc[tt] + bo;
          if (relu) v = fmaxf(v, 0.f);
          int t = g * 8 + tt;
          if (route == 0) {
            out0[(size_t)t * nout + o] = v;
          } else if (route == 1) {
            if (o < E) out0[(size_t)t * E + o] = v;
            else if (o < 2 * E) out1[(size_t)t * E + (o - E)] = v;
            else out2[(size_t)t * E + (o - 2 * E)] = v;
          } else {
            if (o < E) out0[(size_t)t * E + o] = v;
            else out1[(size_t)t * E + (o - E)] = v;
          }
        }
      }
    }
  }
}

__global__ __launch_bounds__(256) void attn_k(
    const float* __restrict__ q, const float* __restrict__ Kc, const float* __restrict__ Vc,
    float* __restrict__ outp, int p0, int nq, int nk_fixed, int causal) {
  const int tid = threadIdx.x;
  const int lane = tid & 63;
  const int u = blockIdx.x * 4 + (tid >> 6);
  if (u >= nq * 64) return;
  const int qi = u >> 6;
  const int r = u & 63;
  const int b = r >> 3, h = r & 7;
  const int nk = causal ? (p0 + qi + 1) : nk_fixed;

  const size_t qoff = (size_t)(qi * B + b) * E + h * DH + lane;
  const float qv = q[qoff];

  float myscore = -INFINITY;
  for (int k = 0; k < nk; ++k) {
    float prod = qv * Kc[(size_t)(k * B + b) * E + h * DH + lane];
    prod = wsum(prod);
    if (lane == k) myscore = prod * 0.125f;
  }
  float m = wmax(myscore);
  float p = (lane < nk) ? expf(myscore - m) : 0.f;
  float denom = wsum(p);
  float a = p / denom;

  float oacc = 0.f;
  for (int k = 0; k < nk; ++k) {
    float ak = __shfl(a, k);
    oacc = fmaf(ak, Vc[(size_t)(k * B + b) * E + h * DH + lane], oacc);
  }
  outp[qoff] = oacc;
}

__global__ __launch_bounds__(256) void add_ln_k(
    const float* __restrict__ xa, const float* __restrict__ xb,
    const float* __restrict__ g, const float* __restrict__ beta,
    float* __restrict__ outp, int ntok) {
  const int tid = threadIdx.x, lane = tid & 63;
  const int t = blockIdx.x * 4 + (tid >> 6);
  if (t >= ntok) return;
  float v[8];
  float s = 0.f;
#pragma unroll
  for (int j = 0; j < 8; ++j) {
    int d = lane + 64 * j;
    v[j] = xa[(size_t)t * E + d] + xb[(size_t)t * E + d];
    s += v[j];
  }
  s = wsum(s);
  float mean = s * (1.f / 512.f);
  float d2 = 0.f;
#pragma unroll
  for (int j = 0; j < 8; ++j) { float dd = v[j] - mean; d2 += dd * dd; }
  d2 = wsum(d2);
  float inv = 1.f / sqrtf(d2 * (1.f / 512.f) + 1e-5f);
#pragma unroll
  for (int j = 0; j < 8; ++j) {
    int d = lane + 64 * j;
    outp[(size_t)t * E + d] = (v[j] - mean) * inv * g[d] + beta[d];
  }
}

// ================= persistent autoregressive decode =================
// blocks 0..63: head-parallel decoder clusters (batch b = bid>>3, head j = bid&7).
//   bid%8 == j  ->  all same-head blocks share an XCD -> decoder weights L2-resident.
// all 256 blocks: logits rows (125 each) + per-block partial argmax.
// grid sync per step: x3flag (8 arrivals) + 32-sharded done counters (8 RMW each).

__global__ __launch_bounds__(NT, 1) void decode_persist_k(
    const float* __restrict__ emb,
    const float* __restrict__ sa_w, const float* __restrict__ sa_b,
    const float* __restrict__ sa_ow, const float* __restrict__ sa_ob,
    const float* __restrict__ ca_w, const float* __restrict__ ca_b,
    const float* __restrict__ ca_ow, const float* __restrict__ ca_ob,
    const float* __restrict__ ff1_w, const float* __restrict__ ff1_b,
    const float* __restrict__ ff2_w, const float* __restrict__ ff2_b,
    const float* __restrict__ ln_g, const float* __restrict__ ln_b,
    const float* __restrict__ out_w, const float* __restrict__ out_b,
    float* __restrict__ kself, float* __restrict__ vself,
    const float* __restrict__ kcross, const float* __restrict__ vcross,
    float* __restrict__ x3buf, float* __restrict__ xstep, float* __restrict__ part,
    float* __restrict__ amaxbuf, float* __restrict__ outp, int* __restrict__ bar) {
  __shared__ __align__(16) float s_x[E];        // current activation vector
  __shared__ __align__(16) float s_q[DH];       // head-j query
  __shared__ __align__(16) float s_att[DH];     // head-j attention output
  __shared__ __align__(16) float s_h[256];      // ff1 slice
  __shared__ __align__(16) float s_tile[8 * E]; // x3 of all batches (logits input)
  __shared__ float s_rv[NT];
  __shared__ int   s_ri[NT];
  __shared__ float s_r1[8], s_r2[8];
  __shared__ float s_pv[8][8];
  __shared__ int   s_pi[8][8];

  const int tid  = threadIdx.x;
  const int lane = tid & 63;
  const int wv   = tid >> 6;          // wave 0..7
  const int g4   = lane >> 2;         // row-in-group 0..15
  const int s4   = lane & 3;          // K-quarter 0..3
  const int bid  = blockIdx.x;
  const int b    = bid >> 3;          // batch (cluster blocks only)
  const int j    = bid & 7;           // head / slice

  int cgen = 0;

  // cluster barrier (8 blocks of batch b)
  auto cl_sync = [&]() {
    ++cgen;
    __syncthreads();
    if (tid == 0) {
      __hip_atomic_fetch_add(&bar[b * 32], 1, __ATOMIC_RELAXED, __HIP_MEMORY_SCOPE_AGENT);
      while (ldci(&bar[b * 32]) < 8 * cgen) __builtin_amdgcn_s_sleep(2);
    }
    __syncthreads();
  };

  // row dot over K=512, 4-lane split with bank-skew; result in all 4 lanes of group
  auto dot512 = [&](const float* Wrow, const float* xin) -> float {
    const f4* Wp = (const f4*)Wrow;
    const f4* Xp = (const f4*)xin;
    float acc = 0.f;
#pragma unroll
    for (int u = 0; u < 32; ++u) {
      int jj = s4 * 32 + ((u + s4) & 31);
      f4 w = Wp[jj], x = Xp[jj];
      acc += w.x * x.x + w.y * x.y + w.z * x.z + w.w * x.w;
    }
    acc += __shfl_xor(acc, 1);
    acc += __shfl_xor(acc, 2);
    return acc;
  };
  auto dot256 = [&](const float* Wseg, const float* xin) -> float {
    const f4* Wp = (const f4*)Wseg;
    const f4* Xp = (const f4*)xin;
    float acc = 0.f;
#pragma unroll
    for (int u = 0; u < 16; ++u) {
      int jj = s4 * 16 + ((u + s4) & 15);
      f4 w = Wp[jj], x = Xp[jj];
      acc += w.x * x.x + w.y * x.y + w.z * x.z + w.w * x.w;
    }
    acc += __shfl_xor(acc, 1);
    acc += __shfl_xor(acc, 2);
    return acc;
  };
  auto dot64 = [&](const float* Wseg, const float* xin) -> float {
    const f4* Wp = (const f4*)Wseg;
    const f4* Xp = (const f4*)xin;
    float acc = 0.f;
#pragma unroll
    for (int u = 0; u < 4; ++u) {
      int jj = s4 * 4 + ((u + s4) & 3);
      f4 w = Wp[jj], x = Xp[jj];
      acc += w.x * x.x + w.y * x.y + w.z * x.z + w.w * x.w;
    }
    acc += __shfl_xor(acc, 1);
    acc += __shfl_xor(acc, 2);
    return acc;
  };

  // block-wide LN of per-thread value (tid==dim) -> dst[tid]
  auto blockLN = [&](float val, const float* gg, const float* be, float* dst) {
    float s1 = wsum(val);
    if (lane == 0) s_r1[wv] = s1;
    __syncthreads();
    float m = 0.f;
#pragma unroll
    for (int w2 = 0; w2 < 8; ++w2) m += s_r1[w2];
    m *= (1.f / 512.f);
    float d = val - m;
    float s2 = wsum(d * d);
    if (lane == 0) s_r2[wv] = s2;
    __syncthreads();
    float var = 0.f;
#pragma unroll
    for (int w2 = 0; w2 < 8; ++w2) var += s_r2[w2];
    var *= (1.f / 512.f);
    float inv = 1.f / sqrtf(var + 1e-5f);
    dst[tid] = d * inv * gg[tid] + be[tid];
    __syncthreads();
  };

  // head-local attention: wave 0, lane = key for scores, lane = dim for output
  auto attn1 = [&](const float* Kbase, const float* Vbase, int nk) {
    if (wv == 0) {
      float sc = -INFINITY;
      if (lane < nk) {
        const f4* Kr = (const f4*)(Kbase + ((size_t)lane * B + b) * E + j * DH);
        const f4* Qp = (const f4*)s_q;
        float a0 = 0.f;
#pragma unroll
        for (int u = 0; u < 16; ++u) {
          f4 kv = Kr[u], qv = Qp[u];
          a0 += kv.x * qv.x + kv.y * qv.y + kv.z * qv.z + kv.w * qv.w;
        }
        sc = a0 * 0.125f;
      }
      float m = wmax(sc);
      float e = (lane < nk) ? expf(sc - m) : 0.f;
      float den = wsum(e);
      float aa = e / den;
      float o = 0.f;
      for (int k2 = 0; k2 < nk; ++k2) {
        float ak = __shfl(aa, k2);
        o = fmaf(ak, Vbase[((size_t)k2 * B + b) * E + j * DH + lane], o);
      }
      s_att[lane] = o;
    }
    __syncthreads();
  };

  for (int i = 0; i < MAXLEN - 1; ++i) {
    const int p = INIT + i;                      // position decoded this step

    if (bid < 64) {
      // ================= decoder cluster =================
      if (j == 0) {
        // ---- token select for batch b ----
        if (i > 0) {
          if (tid < 32) {
            while (ldci(&bar[(18 + tid) * 32]) < 8 * i) __builtin_amdgcn_s_sleep(4);
          }
          __syncthreads();
          if (tid < 256) {
            float2 pr = ldc8(&amaxbuf[(size_t)(tid * 8 + b) * 2]);
            s_rv[tid] = pr.x; s_ri[tid] = (int)pr.y;
          } else { s_rv[tid] = -INFINITY; s_ri[tid] = 0x7fffffff; }
          __syncthreads();
          for (int st2 = 128; st2; st2 >>= 1) {
            if (tid < st2) {
              float ov = s_rv[tid + st2]; int oi = s_ri[tid + st2];
              CMB(s_rv[tid], s_ri[tid], ov, oi);
            }
            __syncthreads();
          }
        } else {
          // step 0: full scan of prefill logits row INIT-1
          const float* row = outp + ((size_t)(INIT - 1) * B + b) * V;
          float bv = -INFINITY; int bi = 0x7fffffff;
          for (int j2 = tid; j2 < V / 2; j2 += NT) {
            float2 vv = ldc8(row + 2 * j2);
            CMB(bv, bi, vv.x, 2 * j2);
            CMB(bv, bi, vv.y, 2 * j2 + 1);
          }
          s_rv[tid] = bv; s_ri[tid] = bi;
          __syncthreads();
          for (int st2 = NT / 2; st2; st2 >>= 1) {
            if (tid < st2) {
              float ov = s_rv[tid + st2]; int oi = s_ri[tid + st2];
              CMB(s_rv[tid], s_ri[tid], ov, oi);
            }
            __syncthreads();
          }
        }
        const int tok = s_ri[0];
        // embed + pe[0] (even dims +0, odd dims +1) ; publish to cluster
        if (tid < 256) {
          int d0 = tid * 2;
          float e0 = emb[(size_t)tok * E + d0];
          float e1 = emb[(size_t)tok * E + d0 + 1] + 1.0f;
          s_x[d0] = e0; s_x[d0 + 1] = e1;
          stc8(&xstep[(size_t)b * E + d0], e0, e1);
        }
        __syncthreads();
        if (tid == 0) stci(&bar[(10 + b) * 32], i + 1);
      } else {
        if (tid == 0) {
          while (ldci(&bar[(10 + b) * 32]) < i + 1) __builtin_amdgcn_s_sleep(4);
        }
        __syncthreads();
        if (tid < 256) {
          float2 vv = ldc8(&xstep[(size_t)b * E + tid * 2]);
          s_x[tid * 2] = vv.x; s_x[tid * 2 + 1] = vv.y;
        }
        __syncthreads();
      }

      // ---- 2 layers ----
      for (int l = 0; l < NL; ++l) {
        // QKV head slice: 192 rows (q,k,v x 64)
        for (int c = wv; c < 12; c += 8) {
          int r = c * 16 + g4;
          int sec = r >> 6, off = r & 63;
          int wr = sec * E + j * DH + off;
          float val = dot512(sa_w + ((size_t)l * 3 * E + wr) * E, s_x);
          if (s4 == 0) {
            val += sa_b[(size_t)l * 3 * E + wr];
            if (sec == 0) s_q[off] = val;
            else if (sec == 1) kself[((size_t)(l * LF + p) * B + b) * E + j * DH + off] = val;
            else               vself[((size_t)(l * LF + p) * B + b) * E + j * DH + off] = val;
          }
        }
        __syncthreads();
        // self-attention (keys 0..p), head-local
        attn1(kself + (size_t)l * LF * B * E, vself + (size_t)l * LF * B * E, p + 1);
        // self out-proj partial: o_j[r] = OW[r, j*64: ] . att
        for (int ps = 0; ps < 4; ++ps) {
          int r = wv * 64 + ps * 16 + g4;
          float val = dot64(sa_ow + ((size_t)l * E + r) * E + j * DH, s_att);
          if (s4 == 0) stc(&part[(((size_t)(l * 3 + 0) * 8 + b) * 8 + j) * E + r], val);
        }
        cl_sync();
        {
          float val = s_x[tid] + sa_ob[(size_t)l * E + tid];
          const float* pb = part + ((size_t)(l * 3 + 0) * 8 + b) * 8 * E + tid;
#pragma unroll
          for (int jj = 0; jj < 8; ++jj) val += ldc(pb + jj * E);
          blockLN(val, ln_g + (size_t)(l * 3 + 0) * E, ln_b + (size_t)(l * 3 + 0) * E, s_x);
        }
        // cross Q head slice
        if (wv < 4) {
          int r = wv * 16 + g4;    // 0..63
          float val = dot512(ca_w + ((size_t)l * 3 * E + j * DH + r) * E, s_x);
          if (s4 == 0) s_q[r] = val + ca_b[(size_t)l * 3 * E + j * DH + r];
        }
        __syncthreads();
        attn1(kcross + (size_t)l * S * B * E, vcross + (size_t)l * S * B * E, S);
        for (int ps = 0; ps < 4; ++ps) {
          int r = wv * 64 + ps * 16 + g4;
          float val = dot64(ca_ow + ((size_t)l * E + r) * E + j * DH, s_att);
          if (s4 == 0) stc(&part[(((size_t)(l * 3 + 1) * 8 + b) * 8 + j) * E + r], val);
        }
        cl_sync();
        {
          float val = s_x[tid] + ca_ob[(size_t)l * E + tid];
          const float* pb = part + ((size_t)(l * 3 + 1) * 8 + b) * 8 * E + tid;
#pragma unroll
          for (int jj = 0; jj < 8; ++jj) val += ldc(pb + jj * E);
          blockLN(val, ln_g + (size_t)(l * 3 + 1) * E, ln_b + (size_t)(l * 3 + 1) * E, s_x);
        }
        // FFN slice j: ff1 rows j*256.. (+relu) then ff2 partial
        for (int c = wv; c < 16; c += 8) {
          int r = c * 16 + g4;     // 0..255
          int wr = j * 256 + r;
          float val = dot512(ff1_w + ((size_t)l * FF + wr) * E, s_x);
          if (s4 == 0) s_h[r] = fmaxf(val + ff1_b[(size_t)l * FF + wr], 0.f);
        }
        __syncthreads();
        for (int ps = 0; ps < 4; ++ps) {
          int r = wv * 64 + ps * 16 + g4;
          float val = dot256(ff2_w + ((size_t)l * E + r) * FF + j * 256, s_h);
          if (s4 == 0) stc(&part[(((size_t)(l * 3 + 2) * 8 + b) * 8 + j) * E + r], val);
        }
        cl_sync();
        {
          float val = s_x[tid] + ff2_b[(size_t)l * E + tid];
          const float* pb = part + ((size_t)(l * 3 + 2) * 8 + b) * 8 * E + tid;
#pragma unroll
          for (int jj = 0; jj < 8; ++jj) val += ldc(pb + jj * E);
          blockLN(val, ln_g + (size_t)(l * 3 + 2) * E, ln_b + (size_t)(l * 3 + 2) * E, s_x);
        }
      }

      // ---- publish x3(b) (block j==0), raise flag on 8th arrival ----
      if (j == 0) {
        if (tid < 256) stc8(&x3buf[(size_t)b * E + tid * 2], s_x[tid * 2], s_x[tid * 2 + 1]);
        __syncthreads();           // drain stc8 before counter bump
        if (tid == 0) {
          int old = __hip_atomic_fetch_add(&bar[8 * 32], 1, __ATOMIC_RELAXED, __HIP_MEMORY_SCOPE_AGENT);
          if (old == 8 * (i + 1) - 1) stci(&bar[9 * 32], i + 1);
        }
      }
    }

    // ================= logits: all 256 blocks =================
    if (tid == 0) {
      while (ldci(&bar[9 * 32]) < i + 1) __builtin_amdgcn_s_sleep(4);
    }
    __syncthreads();
    for (int j2 = tid; j2 < 4 * E; j2 += NT) {
      float2 vv = ldc8(x3buf + 2 * j2);
      s_tile[2 * j2] = vv.x; s_tile[2 * j2 + 1] = vv.y;
    }
    __syncthreads();

    {
      const int idx = wv * 16 + g4;              // 0..127
      const bool valid = idx < 125;
      const int r = bid * 125 + idx;
      float acc[8] = {0, 0, 0, 0, 0, 0, 0, 0};
      if (valid) {
        const f4* Wp = (const f4*)(out_w + (size_t)r * E);
        const f4* Xp = (const f4*)s_tile;
#pragma unroll 8
        for (int u = 0; u < 32; ++u) {
          int jj = s4 * 32 + ((u + s4) & 31);
          f4 w = __builtin_nontemporal_load(Wp + jj);   // don't evict decoder weights
#pragma unroll
          for (int t = 0; t < 8; ++t) {
            f4 x = Xp[t * 128 + jj];
            acc[t] += w.x * x.x + w.y * x.y + w.z * x.z + w.w * x.w;
          }
        }
#pragma unroll
        for (int t = 0; t < 8; ++t) {
          acc[t] += __shfl_xor(acc[t], 1);
          acc[t] += __shfl_xor(acc[t], 2);
          acc[t] += out_b[r];
        }
        if (s4 == 0) {
#pragma unroll
          for (int t = 0; t < 8; ++t)
            stc(&outp[((size_t)p * B + t) * V + r], acc[t]);
        }
      }
      // per-block partial argmax over its 125 rows, per batch
#pragma unroll
      for (int t = 0; t < 8; ++t) {
        float v = valid ? acc[t] : -INFINITY;
        int ix = valid ? r : 0x7fffffff;
#pragma unroll
        for (int off = 1; off < 64; off <<= 1) {
          float ov = __shfl_xor(v, off); int oi = __shfl_xor(ix, off);
          CMB(v, ix, ov, oi);
        }
        if (lane == 0) { s_pv[wv][t] = v; s_pi[wv][t] = ix; }
      }
    }
    __syncthreads();
    if (wv == 0) {
      int t = lane & 7, w2 = lane >> 3;
      float v = s_pv[w2][t]; int ix = s_pi[w2][t];
#pragma unroll
      for (int off = 8; off < 64; off <<= 1) {
        float ov = __shfl_xor(v, off); int oi = __shfl_xor(ix, off);
        CMB(v, ix, ov, oi);
      }
      if (lane < 8) stc8(&amaxbuf[(size_t)(bid * 8 + lane) * 2], v, (float)ix);
    }
    __syncthreads();               // drain logits + amax stores
    if (tid == 0)
      __hip_atomic_fetch_add(&bar[(18 + (bid & 31)) * 32], 1, __ATOMIC_RELAXED, __HIP_MEMORY_SCOPE_AGENT);
  }
}

extern "C" void kernel_launch(void* const* d_in, const int* in_sizes, int n_in,
                              void* d_out, int out_size, void* d_ws, size_t ws_size,
                              hipStream_t stream) {
  const float* enc       = (const float*)d_in[0];
  const int*   transform = (const int*)d_in[1];
  const float* emb       = (const float*)d_in[3];
  const float* sa_w  = (const float*)d_in[4];
  const float* sa_b  = (const float*)d_in[5];
  const float* sa_ow = (const float*)d_in[6];
  const float* sa_ob = (const float*)d_in[7];
  const float* ca_w  = (const float*)d_in[8];
  const float* ca_b  = (const float*)d_in[9];
  const float* ca_ow = (const float*)d_in[10];
  const float* ca_ob = (const float*)d_in[11];
  const float* ff1_w = (const float*)d_in[12];
  const float* ff1_b = (const float*)d_in[13];
  const float* ff2_w = (const float*)d_in[14];
  const float* ff2_b = (const float*)d_in[15];
  const float* ln_g  = (const float*)d_in[16];
  const float* ln_b  = (const float*)d_in[17];
  const float* out_w = (const float*)d_in[18];
  const float* out_b = (const float*)d_in[19];
  float* out = (float*)d_out;

  // workspace layout (floats)
  const size_t SELF_SZ  = (size_t)LF * B * E;    // 143360
  const size_t CROSS_SZ = (size_t)S * B * E;     // 196608
  float* ws     = (float*)d_ws;
  float* xbuf   = ws;                            // prefill embeddings [12*B, E]
  float* kself  = xbuf + (size_t)INIT * B * E;
  float* vself  = kself + NL * SELF_SZ;
  float* kcross = vself + NL * SELF_SZ;
  float* vcross = kcross + NL * CROSS_SZ;
  float* act0   = vcross + NL * CROSS_SZ;        // [96,E] persist: x3/xstep/amax
  float* act1   = act0 + 96 * E;                 // prefill activations
  float* act2   = act1 + 96 * E;
  float* act3   = act2 + 96 * E;
  float* ffb    = act3 + 96 * E;                 // [96,FF] prefill / persist part buf
  int*   bar    = (int*)(ffb + 96 * FF);         // counters/flags (128B-spaced)

  float* x3buf  = act0;                          // [8,E]
  float* xstep  = act0 + 8 * E;                  // [8,E]
  float* amaxb  = act0 + 16 * E;                 // [256,8,2]
  float* partb  = ffb;                           // [6,8,8,E] = 196608 floats

  hipMemsetAsync(bar, 0, 8192, stream);

  // 1) initial embeddings (positions 0..11)
  embed_init_k<<<INIT * B, 128, 0, stream>>>(transform, emb, xbuf);

  // 2) cross-attn K/V caches
  for (int l = 0; l < NL; ++l) {
    gemm_k<E><<<(2 * E) / 4, 256, 0, stream>>>(
        enc, ca_w + ((size_t)l * 3 * E + E) * E, ca_b + (size_t)l * 3 * E + E,
        S * B, 2 * E, 2, 0, kcross + l * CROSS_SZ, vcross + l * CROSS_SZ, nullptr);
  }

  // 3) prefill positions 0..11 (multi-kernel, one-time)
  {
    const int p0 = 0, nq = INIT, ntok = nq * B;
    const float* xin = xbuf;
    for (int l = 0; l < NL; ++l) {
      const float* x = (l == 0) ? xin : act1;
      gemm_k<E><<<(3 * E) / 4, 256, 0, stream>>>(
          x, sa_w + (size_t)l * 3 * E * E, sa_b + (size_t)l * 3 * E, ntok, 3 * E, 1, 0,
          act2, kself + l * SELF_SZ, vself + l * SELF_SZ);
      attn_k<<<nq * 16, 256, 0, stream>>>(act2, kself + l * SELF_SZ, vself + l * SELF_SZ,
                                          act3, p0, nq, 0, 1);
      gemm_k<E><<<E / 4, 256, 0, stream>>>(
          act3, sa_ow + (size_t)l * E * E, sa_ob + (size_t)l * E, ntok, E, 0, 0, act2, nullptr, nullptr);
      add_ln_k<<<(ntok + 3) / 4, 256, 0, stream>>>(
          x, act2, ln_g + (size_t)l * 3 * E, ln_b + (size_t)l * 3 * E, act1, ntok);
      gemm_k<E><<<E / 4, 256, 0, stream>>>(
          act1, ca_w + (size_t)l * 3 * E * E, ca_b + (size_t)l * 3 * E, ntok, E, 0, 0, act2, nullptr, nullptr);
      attn_k<<<nq * 16, 256, 0, stream>>>(act2, kcross + l * CROSS_SZ, vcross + l * CROSS_SZ,
                                          act3, p0, nq, S, 0);
      gemm_k<E><<<E / 4, 256, 0, stream>>>(
          act3, ca_ow + (size_t)l * E * E, ca_ob + (size_t)l * E, ntok, E, 0, 0, act2, nullptr, nullptr);
      add_ln_k<<<(ntok + 3) / 4, 256, 0, stream>>>(
          act1, act2, ln_g + (size_t)l * 3 * E + E, ln_b + (size_t)l * 3 * E + E, act1, ntok);
      gemm_k<E><<<FF / 4, 256, 0, stream>>>(
          act1, ff1_w + (size_t)l * FF * E, ff1_b + (size_t)l * FF, ntok, FF, 0, 1, ffb, nullptr, nullptr);
      gemm_k<FF><<<E / 4, 256, 0, stream>>>(
          ffb, ff2_w + (size_t)l * E * FF, ff2_b + (size_t)l * E, ntok, E, 0, 0, act2, nullptr, nullptr);
      add_ln_k<<<(ntok + 3) / 4, 256, 0, stream>>>(
          act1, act2, ln_g + (size_t)l * 3 * E + 2 * E, ln_b + (size_t)l * 3 * E + 2 * E, act1, ntok);
    }
    gemm_k<E><<<V / 4, 256, 0, stream>>>(
        act1, out_w, out_b, ntok, V, 0, 0, out, nullptr, nullptr);
  }

  // 4) persistent kernel: all 23 autoregressive steps
  decode_persist_k<<<NB, NT, 0, stream>>>(
      emb, sa_w, sa_b, sa_ow, sa_ob, ca_w, ca_b, ca_ow, ca_ob,
      ff1_w, ff1_b, ff2_w, ff2_b, ln_g, ln_b, out_w, out_b,
      kself, vself, kcross, vcross, x3buf, xstep, partb, amaxb, out, bar);
}